// Round 2
// 919.268 us; speedup vs baseline: 1.0729x; 1.0729x over previous
//
#include <hip/hip_runtime.h>
#include <hip/hip_bf16.h>
#include <stdint.h>

#define L_  4
#define D_  1024
#define DK_ 64
#define B_  8
#define S_  512
#define FF_ 4096
#define M_  (B_*S_)      // 4096 rows
#define EPS_ 1e-3f
#define QKVN_ 256        // q|k|v|pad packed width

typedef __bf16 bf16_t;
typedef bf16_t bf16x8 __attribute__((ext_vector_type(8)));
typedef float  f32x4  __attribute__((ext_vector_type(4)));

__device__ __forceinline__ bf16_t f2b(float f) {
    union { float f; uint32_t u; } v; v.f = f;
    uint32_t r = v.u + 0x7fff + ((v.u >> 16) & 1);   // RNE
    uint16_t h = (uint16_t)(r >> 16);
    bf16_t o; __builtin_memcpy(&o, &h, 2); return o;
}

__device__ __forceinline__ void gl2lds16(const bf16_t* g, bf16_t* l) {
    __builtin_amdgcn_global_load_lds(
        (__attribute__((address_space(1))) void*)g,
        (__attribute__((address_space(3))) void*)l, 16, 0, 0);
}

// ---------------- embed ----------------
__global__ void embed_kernel(const int* __restrict__ seq, const float* __restrict__ emb,
                             const float* __restrict__ pes, float* __restrict__ x,
                             bf16_t* __restrict__ xb) {
    int idx = blockIdx.x * 256 + threadIdx.x;
    int md  = idx >> 10;
    int d   = idx & (D_ - 1);
    int s   = md & (S_ - 1);
    float v = emb[(size_t)seq[md] * D_ + d] + pes[s * D_];
    x[idx] = v;
    xb[idx] = f2b(v);
}

// ---------------- fused per-layer weight prep ----------------
// 32x32 transpose+cvt tile: src[K,N] fp32 -> dst[N,K] bf16
__device__ __forceinline__ void tile_tr(const float* __restrict__ src, bf16_t* __restrict__ dst,
                                        int K, int N, int kb, int nb, float (*t)[33]) {
    int k0 = kb * 32, n0 = nb * 32;
    int c = threadIdx.x & 31, r = threadIdx.x >> 5;   // r = 0..7
    #pragma unroll
    for (int i = 0; i < 4; i++)
        t[r + i * 8][c] = src[(size_t)(k0 + r + i * 8) * N + n0 + c];
    __syncthreads();
    #pragma unroll
    for (int i = 0; i < 4; i++)
        dst[(size_t)(n0 + r + i * 8) * K + k0 + c] = f2b(t[c][r + i * 8]);
}

// one launch per layer: w1(4096) | w2(4096) | wq,wk,wv(192) | wo(64) | zero(16) | bias(1)
__global__ void prep_weights(const float* __restrict__ wq, const float* __restrict__ wk,
                             const float* __restrict__ wv, const float* __restrict__ wo,
                             const float* __restrict__ w1, const float* __restrict__ w2,
                             const float* __restrict__ bq, const float* __restrict__ bk,
                             const float* __restrict__ bv,
                             bf16_t* __restrict__ wqkvt, bf16_t* __restrict__ wot,
                             bf16_t* __restrict__ w1t, bf16_t* __restrict__ w2t,
                             float* __restrict__ bqkv) {
    __shared__ float t[32][33];
    int bid = blockIdx.x;
    if (bid < 4096) {                       // w1: K=D_, N=FF_
        tile_tr(w1, w1t, D_, FF_, bid & 31, bid >> 5, t);
    } else if (bid < 8192) {                // w2: K=FF_, N=D_
        int rem = bid - 4096;
        tile_tr(w2, w2t, FF_, D_, rem & 127, rem >> 7, t);
    } else if (bid < 8384) {                // wq/wk/wv: K=D_, N=64
        int rem = bid - 8192;
        int which = rem >> 6; rem &= 63;
        const float* src = which == 0 ? wq : (which == 1 ? wk : wv);
        tile_tr(src, wqkvt + (size_t)which * 64 * D_, D_, DK_, rem & 31, rem >> 5, t);
    } else if (bid < 8448) {                // wo: K=64, N=D_
        int rem = bid - 8384;
        tile_tr(wo, wot, DK_, D_, rem & 1, rem >> 1, t);
    } else if (bid < 8464) {                // zero pad rows 192..255 of wqkvt
        int rem = bid - 8448;
        bf16_t* z = wqkvt + (size_t)192 * D_ + rem * 4096;
        for (int i = threadIdx.x; i < 4096; i += 256) z[i] = (bf16_t)0.f;
    } else {                                // bias pack
        int n = threadIdx.x;
        float v = 0.f;
        if      (n <  64) v = bq[n];
        else if (n < 128) v = bk[n - 64];
        else if (n < 192) v = bv[n - 128];
        bqkv[n] = v;
    }
}

// ---------------- bf16 MFMA GEMM, coalesced + conflict-free staging ----------------
// LDS layout: elem(row, kchunk) at row*64 + ((kchunk ^ (row&7))*8)   [elements, BK=64, 8-elem chunks]
// Staging instr = 8 rows x 128 B; lane l -> row l>>3, chunk (l&7)^(l>>3)  => global 128-B segments.
// Fragment ds_read_b128: per quad-group, chunk' = const ^ (lm&7) => 2 lanes/bank = free.
// MODE 1: Cb = relu(acc+bias) bf16          (FFN1)
// MODE 2: partial bf16, no bias: Cb + z*strideZ  (QKV z4, FFN2 z2)
// MODE 3: fused BN epilogue: o = g*(X + acc + bias - mu)*rsqrt(var+eps) + b -> Xf, Xb   (wo proj)
template<int MODE>
__global__ __launch_bounds__(256)
void gemm_mfma3(const bf16_t* __restrict__ A, const bf16_t* __restrict__ Bt,
                const float* __restrict__ bias, bf16_t* __restrict__ Cb,
                const float* __restrict__ Xin, float* __restrict__ Xf, bf16_t* __restrict__ Xb,
                const float* __restrict__ g, const float* __restrict__ bb,
                const float* __restrict__ mu, const float* __restrict__ var,
                int N, int K, int kChunk, size_t strideZ) {
    __shared__ bf16_t As[128 * 64];
    __shared__ bf16_t Bs[128 * 64];
    const int tid  = threadIdx.x;
    const int w    = tid >> 6, lane = tid & 63;
    const int wm   = w >> 1,   wn   = w & 1;
    const int lm   = lane & 15, quad = lane >> 4;
    const int m0 = blockIdx.y * 128, n0 = blockIdx.x * 128;
    const int kBeg = blockIdx.z * kChunk, kEnd = kBeg + kChunk;
    const int lrow = lane >> 3;              // 0..7
    const int lk   = (lane & 7) ^ lrow;      // xor-swizzled chunk to fetch

    f32x4 acc[4][4];
    #pragma unroll
    for (int i = 0; i < 4; i++)
        #pragma unroll
        for (int j = 0; j < 4; j++) acc[i][j] = (f32x4){0.f, 0.f, 0.f, 0.f};

    for (int k0 = kBeg; k0 < kEnd; k0 += 64) {
        #pragma unroll
        for (int i = 0; i < 4; i++) {
            const int r0 = w * 32 + i * 8;
            gl2lds16(A  + (size_t)(m0 + r0 + lrow) * K + k0 + lk * 8, As + r0 * 64);
            gl2lds16(Bt + (size_t)(n0 + r0 + lrow) * K + k0 + lk * 8, Bs + r0 * 64);
        }
        __syncthreads();
        #pragma unroll
        for (int s = 0; s < 2; s++) {
            bf16x8 af[4], bfr[4];
            #pragma unroll
            for (int mi = 0; mi < 4; mi++) {
                const int ra = wm * 64 + mi * 16 + lm;
                af[mi] = *(const bf16x8*)(As + ra * 64 + (((s * 4 + quad) ^ (lm & 7)) * 8));
            }
            #pragma unroll
            for (int ni = 0; ni < 4; ni++) {
                const int rb = wn * 64 + ni * 16 + lm;
                bfr[ni] = *(const bf16x8*)(Bs + rb * 64 + (((s * 4 + quad) ^ (lm & 7)) * 8));
            }
            #pragma unroll
            for (int mi = 0; mi < 4; mi++)
                #pragma unroll
                for (int ni = 0; ni < 4; ni++)
                    acc[mi][ni] = __builtin_amdgcn_mfma_f32_16x16x32_bf16(
                        af[mi], bfr[ni], acc[mi][ni], 0, 0, 0);
        }
        __syncthreads();
    }

    bf16_t* Pz = (MODE == 2) ? Cb + (size_t)blockIdx.z * strideZ : Cb;

    #pragma unroll
    for (int ni = 0; ni < 4; ni++) {
        const int col = n0 + wn * 64 + ni * 16 + lm;
        float bv = 0.f, gv = 0.f, bbv = 0.f, muv = 0.f, rsv = 0.f;
        if (MODE != 2) bv = bias[col];
        if (MODE == 3) {
            gv = g[col]; bbv = bb[col]; muv = mu[col];
            rsv = rsqrtf(var[col] + EPS_);
        }
        #pragma unroll
        for (int mi = 0; mi < 4; mi++) {
            const int rbase = m0 + wm * 64 + mi * 16 + quad * 4;
            #pragma unroll
            for (int r = 0; r < 4; r++) {
                const size_t idx = (size_t)(rbase + r) * N + col;
                float v = acc[mi][ni][r] + bv;
                if (MODE == 1) Cb[idx] = f2b(fmaxf(v, 0.f));
                if (MODE == 2) Pz[idx] = f2b(v);
                if (MODE == 3) {
                    float s = Xin[idx] + v;
                    float o = gv * (s - muv) * rsv + bbv;
                    Xf[idx] = o;
                    Xb[idx] = f2b(o);
                }
            }
        }
    }
}

// qkv partial sum (4 bf16 partials in d_out) + bias -> bf16 qkv
__global__ void qkv_reduce(const bf16_t* __restrict__ P, const float* __restrict__ bias,
                           bf16_t* __restrict__ dst) {
    int idx = blockIdx.x * 256 + threadIdx.x;    // M_*QKVN_
    int n = idx & (QKVN_ - 1);
    float s = bias[n];
    #pragma unroll
    for (int zz = 0; zz < 4; zz++) s += (float)P[(size_t)zz * M_ * QKVN_ + idx];
    dst[idx] = f2b(s);
}

// ---------------- V transpose: qkv v-slice [b][k=512][n=64] -> Vt [b][n=64][k=512] ----------------
__global__ void vt_kernel(const bf16_t* __restrict__ qkv, bf16_t* __restrict__ Vt) {
    int b = blockIdx.y, k0 = blockIdx.x * 64;        // grid (S/64, B)
    const bf16_t* vb = qkv + (size_t)b * S_ * QKVN_ + 128;
    __shared__ bf16_t t[64][65];
    int c = threadIdx.x & 63, r4 = threadIdx.x >> 6;
    #pragma unroll
    for (int i = 0; i < 16; i++) {
        int k = i * 4 + r4;
        t[c][k] = vb[(size_t)(k0 + k) * QKVN_ + c];   // coalesced 128B row reads
    }
    __syncthreads();
    #pragma unroll
    for (int i = 0; i < 16; i++) {
        int d = i * 4 + r4;
        Vt[((size_t)b * DK_ + d) * S_ + k0 + c] = t[d][c];  // coalesced 128B row writes
    }
}

// ---------------- fused attention: score + softmax + PV in one launch ----------------
// grid (S/64, B), 256 threads (4 waves). Per WG: 64 q-rows x all 512 keys.
// Q,K fragments read directly from global (L2-hot, no intra-WG reuse for K).
// P round-trips through 64KB swizzled LDS (the C-layout -> A-frag transpose medium).
// V pre-transposed (Vt [n][k]) staged via global_load_lds with the proven GEMM swizzle.
// LDS: Ps 64K + Vs 64K + rowred 1K = 129 KB (one WG/CU; grid is 64 WGs).
__global__ __launch_bounds__(256)
void attn_fused(const bf16_t* __restrict__ qkv, const bf16_t* __restrict__ Vt,
                bf16_t* __restrict__ hdb) {
    const int b  = blockIdx.y;
    const int i0 = blockIdx.x * 64;
    const bf16_t* qb  = qkv + (size_t)b * S_ * QKVN_;
    const bf16_t* kb  = qb + 64;
    const bf16_t* vtb = Vt + (size_t)b * DK_ * S_;

    // layout for Ps/Vs: [ktile(8)][row(64)][64 elems], inner 64-elem tile XOR-swizzled
    __shared__ bf16_t Ps[8 * 64 * 64];
    __shared__ bf16_t Vs[8 * 64 * 64];
    __shared__ float  rowred[4][64];

    const int tid  = threadIdx.x;
    const int w    = tid >> 6, lane = tid & 63;
    const int lm   = lane & 15, quad = lane >> 4;
    const int lrow = lane >> 3;
    const int lk   = (lane & 7) ^ lrow;

    // ---- stage Vt -> Vs early (completion enforced by the vmcnt(0) before barriers) ----
    #pragma unroll
    for (int i = 0; i < 16; i++) {
        const int r0 = w * 16 + (i & 1) * 8;
        const int kt = i >> 1;
        gl2lds16(vtb + (size_t)(r0 + lrow) * S_ + kt * 64 + lk * 8,
                 Vs + kt * 4096 + r0 * 64);
    }

    // ---- scores: wave w covers key cols w*128..w*128+127, all 64 q-rows ----
    f32x4 acc[4][8];
    #pragma unroll
    for (int mi = 0; mi < 4; mi++)
        #pragma unroll
        for (int ni = 0; ni < 8; ni++) acc[mi][ni] = (f32x4){0.f, 0.f, 0.f, 0.f};

    #pragma unroll
    for (int s = 0; s < 2; s++) {
        bf16x8 af[4], bfr[8];
        #pragma unroll
        for (int mi = 0; mi < 4; mi++)
            af[mi] = *(const bf16x8*)(qb + (size_t)(i0 + mi * 16 + lm) * QKVN_ + s * 32 + quad * 8);
        #pragma unroll
        for (int ni = 0; ni < 8; ni++)
            bfr[ni] = *(const bf16x8*)(kb + (size_t)(w * 128 + ni * 16 + lm) * QKVN_ + s * 32 + quad * 8);
        #pragma unroll
        for (int mi = 0; mi < 4; mi++)
            #pragma unroll
            for (int ni = 0; ni < 8; ni++)
                acc[mi][ni] = __builtin_amdgcn_mfma_f32_16x16x32_bf16(
                    af[mi], bfr[ni], acc[mi][ni], 0, 0, 0);
    }
    #pragma unroll
    for (int mi = 0; mi < 4; mi++)
        #pragma unroll
        for (int ni = 0; ni < 8; ni++) acc[mi][ni] *= 0.125f;   // 1/sqrt(DK)

    // ---- per-row max: reduce over ni then over lm (16-lane groups) ----
    float rmax[4][4];
    #pragma unroll
    for (int mi = 0; mi < 4; mi++)
        #pragma unroll
        for (int r = 0; r < 4; r++) {
            float m = acc[mi][0][r];
            #pragma unroll
            for (int ni = 1; ni < 8; ni++) m = fmaxf(m, acc[mi][ni][r]);
            #pragma unroll
            for (int off = 1; off < 16; off <<= 1) m = fmaxf(m, __shfl_xor(m, off, 64));
            rmax[mi][r] = m;
        }
    if (lm == 0) {
        #pragma unroll
        for (int mi = 0; mi < 4; mi++)
            #pragma unroll
            for (int r = 0; r < 4; r++)
                rowred[w][mi * 16 + quad * 4 + r] = rmax[mi][r];
    }
    __syncthreads();
    float gmax[4][4];
    #pragma unroll
    for (int mi = 0; mi < 4; mi++)
        #pragma unroll
        for (int r = 0; r < 4; r++) {
            const int row = mi * 16 + quad * 4 + r;
            gmax[mi][r] = fmaxf(fmaxf(rowred[0][row], rowred[1][row]),
                                fmaxf(rowred[2][row], rowred[3][row]));
        }
    __syncthreads();   // all maxes consumed before rowred is reused for sums

    // ---- p = exp(s - max) -> bf16 into Ps; accumulate row sums of the rounded values ----
    float rsum[4][4];
    #pragma unroll
    for (int mi = 0; mi < 4; mi++)
        #pragma unroll
        for (int r = 0; r < 4; r++) rsum[mi][r] = 0.f;
    #pragma unroll
    for (int mi = 0; mi < 4; mi++) {
        #pragma unroll
        for (int ni = 0; ni < 8; ni++) {
            const int key = w * 128 + ni * 16 + lm;
            const int kt  = key >> 6;
            const int ck  = (key >> 3) & 7;
            #pragma unroll
            for (int r = 0; r < 4; r++) {
                const int m = mi * 16 + quad * 4 + r;
                float p = __expf(acc[mi][ni][r] - gmax[mi][r]);
                bf16_t pb = f2b(p);
                rsum[mi][r] += (float)pb;
                Ps[kt * 4096 + m * 64 + ((ck ^ (m & 7)) * 8) + (key & 7)] = pb;
            }
        }
    }
    #pragma unroll
    for (int mi = 0; mi < 4; mi++)
        #pragma unroll
        for (int r = 0; r < 4; r++) {
            float s = rsum[mi][r];
            #pragma unroll
            for (int off = 1; off < 16; off <<= 1) s += __shfl_xor(s, off, 64);
            rsum[mi][r] = s;
        }
    if (lm == 0) {
        #pragma unroll
        for (int mi = 0; mi < 4; mi++)
            #pragma unroll
            for (int r = 0; r < 4; r++)
                rowred[w][mi * 16 + quad * 4 + r] = rsum[mi][r];
    }
    __syncthreads();   // Ps + row sums visible; Vt staging drained (vmcnt(0))

    // ---- PV: wave w owns out rows w*16..w*16+15, full K=512 ----
    f32x4 accO[4];
    #pragma unroll
    for (int ni = 0; ni < 4; ni++) accO[ni] = (f32x4){0.f, 0.f, 0.f, 0.f};
    #pragma unroll
    for (int ks = 0; ks < 16; ks++) {
        const int kt = ks >> 1;
        const int co = (ks & 1) * 4 + quad;
        bf16x8 af = *(const bf16x8*)(Ps + kt * 4096 + (w * 16 + lm) * 64 + ((co ^ (lm & 7)) * 8));
        #pragma unroll
        for (int ni = 0; ni < 4; ni++) {
            bf16x8 bfr = *(const bf16x8*)(Vs + kt * 4096 + (ni * 16 + lm) * 64 + ((co ^ (lm & 7)) * 8));
            accO[ni] = __builtin_amdgcn_mfma_f32_16x16x32_bf16(af, bfr, accO[ni], 0, 0, 0);
        }
    }

    // ---- normalize + write ----
    #pragma unroll
    for (int r = 0; r < 4; r++) {
        const int row = w * 16 + quad * 4 + r;
        const float tot = rowred[0][row] + rowred[1][row] + rowred[2][row] + rowred[3][row];
        const float inv = 1.0f / tot;
        #pragma unroll
        for (int ni = 0; ni < 4; ni++)
            hdb[(size_t)(b * S_ + i0 + row) * DK_ + ni * 16 + lm] = f2b(accO[ni][r] * inv);
    }
}

// bn2: dst = BN(x + bias + sum of 2 bf16 K-split partials (in d_out))
__global__ void bn_residual2(const float* __restrict__ x, const bf16_t* __restrict__ p,
                             const float* __restrict__ bias,
                             const float* __restrict__ g, const float* __restrict__ b,
                             const float* __restrict__ mu, const float* __restrict__ var,
                             float* __restrict__ dst, bf16_t* __restrict__ dstb) {
    int idx = blockIdx.x * 256 + threadIdx.x;
    int d = idx & (D_ - 1);
    float r = bias[d] + (float)p[idx] + (float)p[(size_t)M_ * D_ + idx];
    float s = x[idx] + r;
    float o = g[d] * (s - mu[d]) * rsqrtf(var[d] + EPS_) + b[d];
    dst[idx] = o;
    dstb[idx] = f2b(o);
}

extern "C" void kernel_launch(void* const* d_in, const int* in_sizes, int n_in,
                              void* d_out, int out_size, void* d_ws, size_t ws_size,
                              hipStream_t stream) {
    const int*   seq = (const int*)  d_in[0];
    const float* emb = (const float*)d_in[1];
    const float* pes = (const float*)d_in[2];
    const float* wq  = (const float*)d_in[3];
    const float* bq  = (const float*)d_in[4];
    const float* wk  = (const float*)d_in[5];
    const float* bk  = (const float*)d_in[6];
    const float* wv  = (const float*)d_in[7];
    const float* bv  = (const float*)d_in[8];
    const float* wo  = (const float*)d_in[9];
    const float* bo  = (const float*)d_in[10];
    const float* ag  = (const float*)d_in[11];
    const float* ab  = (const float*)d_in[12];
    const float* am  = (const float*)d_in[13];
    const float* av  = (const float*)d_in[14];
    const float* w1  = (const float*)d_in[15];
    const float* b1  = (const float*)d_in[16];
    const float* w2  = (const float*)d_in[17];
    const float* b2  = (const float*)d_in[18];
    const float* fg  = (const float*)d_in[19];
    const float* fb  = (const float*)d_in[20];
    const float* fm  = (const float*)d_in[21];
    const float* fv  = (const float*)d_in[22];
    float* out = (float*)d_out;

    // workspace carve
    char* p = (char*)d_ws;
    auto alloc = [&](size_t bytes) { char* q = p; p += (bytes + 255) & ~(size_t)255; return q; };
    float*  X     = (float*) alloc((size_t)M_ * D_ * 4);        // 16 MB
    bf16_t* Xb    = (bf16_t*)alloc((size_t)M_ * D_ * 2);        //  8 MB
    bf16_t* qkvb  = (bf16_t*)alloc((size_t)M_ * QKVN_ * 2);     //  2 MB
    bf16_t* Vtb   = (bf16_t*)alloc((size_t)B_ * DK_ * S_ * 2);  // .5 MB
    bf16_t* hdb   = (bf16_t*)alloc((size_t)M_ * DK_ * 2);       // .5 MB
    bf16_t* hb    = (bf16_t*)alloc((size_t)M_ * FF_ * 2);       // 32 MB
    bf16_t* w1t   = (bf16_t*)alloc((size_t)FF_ * D_ * 2);       //  8 MB
    bf16_t* w2t   = (bf16_t*)alloc((size_t)D_ * FF_ * 2);       //  8 MB
    bf16_t* wqkvt = (bf16_t*)alloc((size_t)QKVN_ * D_ * 2);     // .5 MB
    bf16_t* wot   = (bf16_t*)alloc((size_t)D_ * DK_ * 2);       // .125 MB
    float*  bqkv  = (float*) alloc(QKVN_ * 4);

    embed_kernel<<<M_ * D_ / 256, 256, 0, stream>>>(seq, emb, pes, X, Xb);

    for (int l = 0; l < L_; l++) {
        // --- fused weight prep (1 launch) ---
        prep_weights<<<8465, 256, 0, stream>>>(
            wq + (size_t)l * D_ * DK_, wk + (size_t)l * D_ * DK_, wv + (size_t)l * D_ * DK_,
            wo + (size_t)l * DK_ * D_, w1 + (size_t)l * D_ * FF_, w2 + (size_t)l * FF_ * D_,
            bq + l * DK_, bk + l * DK_, bv + l * DK_,
            wqkvt, wot, w1t, w2t, bqkv);

        // --- QKV: split-K=4, bf16 partials in d_out (8 MB) ---
        gemm_mfma3<2><<<dim3(QKVN_ / 128, M_ / 128, 4), 256, 0, stream>>>(
            Xb, wqkvt, nullptr, (bf16_t*)out, nullptr, nullptr, nullptr,
            nullptr, nullptr, nullptr, nullptr, QKVN_, D_, D_ / 4, (size_t)M_ * QKVN_);
        qkv_reduce<<<M_ * QKVN_ / 256, 256, 0, stream>>>((const bf16_t*)out, bqkv, qkvb);

        // --- attention: V transpose + single fused kernel ---
        vt_kernel<<<dim3(S_ / 64, B_), 256, 0, stream>>>(qkvb, Vtb);
        attn_fused<<<dim3(S_ / 64, B_), 256, 0, stream>>>(qkvb, Vtb, hdb);

        // --- output proj with fused BN1 epilogue ---
        gemm_mfma3<3><<<dim3(D_ / 128, M_ / 128, 1), 256, 0, stream>>>(
            hdb, wot, bo + l * D_, nullptr, X, X, Xb,
            ag + l * D_, ab + l * D_, am + l * D_, av + l * D_, D_, DK_, DK_, 0);

        // --- FFN1 (bf16 + relu) ---
        gemm_mfma3<1><<<dim3(FF_ / 128, M_ / 128, 1), 256, 0, stream>>>(
            Xb, w1t, b1 + l * FF_, hb, nullptr, nullptr, nullptr,
            nullptr, nullptr, nullptr, nullptr, FF_, D_, D_, 0);

        // --- FFN2: split-K=2, bf16 partials in d_out (16 MB) ---
        gemm_mfma3<2><<<dim3(D_ / 128, M_ / 128, 2), 256, 0, stream>>>(
            hb, w2t, nullptr, (bf16_t*)out, nullptr, nullptr, nullptr,
            nullptr, nullptr, nullptr, nullptr, D_, FF_, FF_ / 2, (size_t)M_ * D_);

        bn_residual2<<<M_ * D_ / 256, 256, 0, stream>>>(
            X, (const bf16_t*)out, b2 + l * D_,
            fg + l * D_, fb + l * D_, fm + l * D_, fv + l * D_, X, Xb);
        if (l == L_ - 1)
            hipMemcpyAsync(out, X, (size_t)M_ * D_ * 4, hipMemcpyDeviceToDevice, stream);
    }
}